// Round 17
// baseline (147.626 us; speedup 1.0000x reference)
//
#include <hip/hip_runtime.h>
#include <cstdint>

#define B_ 16
#define C_ 1024
#define Q_ 128
#define H_ 768
#define OSTR (4 * H_)  // 3072

typedef __attribute__((ext_vector_type(8))) short bf16x8;
typedef __attribute__((ext_vector_type(4))) float f32x4;
typedef __attribute__((ext_vector_type(4))) int int4v;

__device__ __forceinline__ unsigned short f2bf(float x) {
  union { float f; unsigned u; } v; v.f = x;
  unsigned r = v.u + 0x7FFFu + ((v.u >> 16) & 1u);
  return (unsigned short)(r >> 16);
}
__device__ __forceinline__ unsigned pk2(float a, float b) {
  return (unsigned)f2bf(a) | ((unsigned)f2bf(b) << 16);
}
__device__ __forceinline__ float bf2f(unsigned short u) {
  union { unsigned u; float f; } t; t.u = ((unsigned)u) << 16; return t.f;
}

// four-segment fp32 -> bf16 (context, query, Wc, Wq); NT loads.
__global__ __launch_bounds__(256) void f2bf4_kernel(
    const float* __restrict__ s0, unsigned short* __restrict__ d0, int n0,
    const float* __restrict__ s1, unsigned short* __restrict__ d1, int n1,
    const float* __restrict__ s2, unsigned short* __restrict__ d2, int n2,
    const float* __restrict__ s3, unsigned short* __restrict__ d3, int n3) {
  int i = blockIdx.x * 256 + threadIdx.x;
  const float* s;
  unsigned short* d;
  if (i < n0) { s = s0; d = d0; }
  else if ((i -= n0) < n1) { s = s1; d = d1; }
  else if ((i -= n1) < n2) { s = s2; d = d2; }
  else if ((i -= n2) < n3) { s = s3; d = d3; }
  else return;
  f32x4 a = __builtin_nontemporal_load((const f32x4*)s + 2 * i);
  f32x4 b = __builtin_nontemporal_load((const f32x4*)s + 2 * i + 1);
  int4v o;
  o[0] = (int)pk2(a[0], a[1]); o[1] = (int)pk2(a[2], a[3]);
  o[2] = (int)pk2(b[0], b[1]); o[3] = (int)pk2(b[2], b[3]);
  ((int4v*)d)[i] = o;
}

// Combined projection GEMM, one launch, 864 blocks:
//   blocks [0,768):  ctx proj -> bf16 ctxp (LDS bf16-transpose, int4v stores)
//   blocks [768,864): qry proj -> bf16 qryW=v*watt + bf16 qryT (transposed)
__global__ __launch_bounds__(256) void proj_kernel(
    const unsigned short* __restrict__ ctxb, const unsigned short* __restrict__ Wcb,
    const float* __restrict__ bc, unsigned short* __restrict__ ctxp,
    const unsigned short* __restrict__ qinb, const unsigned short* __restrict__ Wqb,
    const float* __restrict__ bq, unsigned short* __restrict__ qryW,
    unsigned short* __restrict__ qryT, const float* __restrict__ watt) {
  __shared__ __align__(16) unsigned char smem[33792];
  unsigned short* As = (unsigned short*)smem;
  unsigned short* Ws = (unsigned short*)(smem + 8192);
  const int tid = threadIdx.x;
  const int lane = tid & 63;
  const int w = tid >> 6;
  const int bid = (int)blockIdx.x;
  const bool isC = bid < 768;
  int orig, gm, gn;
  const unsigned short *Ap, *Bp;
  const float* bias;
  if (isC) {
    orig = (bid & 7) * 96 + (bid >> 3);
    gm = (orig / 6) * 128; gn = (orig % 6) * 128;
    Ap = ctxb + (size_t)gm * H_; Bp = Wcb + (size_t)gn * H_; bias = bc;
  } else {
    const int b2 = bid - 768;
    orig = (b2 & 7) * 12 + (b2 >> 3);
    gm = (orig / 6) * 128; gn = (orig % 6) * 128;
    Ap = qinb + (size_t)gm * H_; Bp = Wqb + (size_t)gn * H_; bias = bq;
  }
  const int wrA = (w >> 1) * 64;
  const int wcB = (w & 1) * 64;
  const int fr = lane & 15;
  const int fq = lane >> 4;

  auto stage128 = [&](const unsigned short* __restrict__ G, unsigned short* S, int k0) {
#pragma unroll
    for (int r = 0; r < 2; ++r) {
      const int c = r * 256 + tid;
      const int row = c >> 2, sub = c & 3;
      const unsigned short* g = G + (size_t)row * H_ + k0 + sub * 8;
      unsigned short* l = S + (size_t)(r * 256 + w * 64) * 8;  // wave-uniform base
      __builtin_amdgcn_global_load_lds(
          (const __attribute__((address_space(1))) void*)g,
          (__attribute__((address_space(3))) void*)l, 16, 0, 0);
    }
  };

  f32x4 acc[4][4];
#pragma unroll
  for (int i = 0; i < 4; ++i)
#pragma unroll
    for (int j = 0; j < 4; ++j)
#pragma unroll
      for (int e = 0; e < 4; ++e) acc[i][j][e] = 0.f;

  for (int k0 = 0; k0 < H_; k0 += 32) {
    stage128(Ap, As, k0);
    stage128(Bp, Ws, k0);
    __syncthreads();
    bf16x8 af[4], wf[4];
#pragma unroll
    for (int i = 0; i < 4; ++i)
      af[i] = *(const bf16x8*)(As + (wrA + i * 16 + fr) * 32 + fq * 8);
#pragma unroll
    for (int j = 0; j < 4; ++j)
      wf[j] = *(const bf16x8*)(Ws + (wcB + j * 16 + fr) * 32 + fq * 8);
#pragma unroll
    for (int i = 0; i < 4; ++i)
#pragma unroll
      for (int j = 0; j < 4; ++j)
        acc[i][j] = __builtin_amdgcn_mfma_f32_16x16x32_bf16(af[i], wf[j], acc[i][j], 0, 0, 0);
    __syncthreads();
  }

  if (isC) {
    unsigned short* tr16 = (unsigned short*)smem;
    float bj[4];
#pragma unroll
    for (int j = 0; j < 4; ++j) bj[j] = bias[gn + wcB + j * 16 + fr];
#pragma unroll
    for (int i = 0; i < 4; ++i)
#pragma unroll
      for (int j = 0; j < 4; ++j)
#pragma unroll
        for (int r = 0; r < 4; ++r)
          tr16[(wrA + i * 16 + fq * 4 + r) * 132 + wcB + j * 16 + fr] =
              f2bf(acc[i][j][r] + bj[j]);
    __syncthreads();
#pragma unroll
    for (int k = 0; k < 8; ++k) {
      const int f = k * 256 + tid;
      const int row = f >> 4, c8 = (f & 15) << 3;
      int4v v = *(const int4v*)&tr16[row * 132 + c8];
      *(int4v*)&ctxp[(size_t)(gm + row) * H_ + gn + c8] = v;
    }
  } else {
#pragma unroll
    for (int i = 0; i < 4; ++i) {
#pragma unroll
      for (int j = 0; j < 4; ++j) {
        const int n = gn + wcB + j * 16 + fr;
        const float bias_n = bias[n];
        const float wv = watt[n];
        ushort4 t4;
#pragma unroll
        for (int r = 0; r < 4; ++r) {
          const size_t m = (size_t)gm + wrA + i * 16 + fq * 4 + r;
          float v = acc[i][j][r] + bias_n;
          qryW[m * H_ + n] = f2bf(v * wv);
          (&t4.x)[r] = f2bf(v);
        }
        const int bidx = gm >> 7;
        const int q0 = wrA + i * 16 + fq * 4;
        *(ushort4*)(qryT + ((size_t)bidx * H_ + n) * Q_ + q0) = t4;
      }
    }
  }
}

// sim GEMM (64x128, full q) -> fused row-softmax -> bf16 alpha + q2c
__global__ __launch_bounds__(256) void sim_kernel(
    const unsigned short* __restrict__ A, const unsigned short* __restrict__ Bm,
    unsigned short* __restrict__ alpha, const float* __restrict__ cmask,
    const float* __restrict__ qmask, float* __restrict__ q2c) {
  __shared__ __align__(16) unsigned char smem[16384];
  __shared__ float pmS[2][64];
  __shared__ float psS[2][64];
  unsigned short* As = (unsigned short*)smem;
  unsigned short* Ws = (unsigned short*)(smem + 4096);
  const int tid = threadIdx.x;
  const int lane = tid & 63;
  const int w = tid >> 6;
  const int orig = ((int)blockIdx.x & 7) * 32 + ((int)blockIdx.x >> 3);
  const int bb = orig >> 4;
  const int gm = bb * C_ + (orig & 15) * 64;
  const int wrA = (w >> 1) * 32;
  const int wcB = (w & 1) * 64;
  const int fr = lane & 15;
  const int fq = lane >> 4;
  const unsigned short* Ap = A + (size_t)gm * H_;
  const unsigned short* Bp = Bm + (size_t)bb * Q_ * H_;

  f32x4 acc[2][4];
#pragma unroll
  for (int i = 0; i < 2; ++i)
#pragma unroll
    for (int j = 0; j < 4; ++j)
#pragma unroll
      for (int e = 0; e < 4; ++e) acc[i][j][e] = 0.f;

  for (int k0 = 0; k0 < H_; k0 += 32) {
    {
      const int row = tid >> 2, sub = tid & 3;
      const unsigned short* g = Ap + (size_t)row * H_ + k0 + sub * 8;
      unsigned short* l = As + (size_t)(w * 64) * 8;
      __builtin_amdgcn_global_load_lds(
          (const __attribute__((address_space(1))) void*)g,
          (__attribute__((address_space(3))) void*)l, 16, 0, 0);
    }
#pragma unroll
    for (int r = 0; r < 2; ++r) {
      const int c = r * 256 + tid;
      const int row = c >> 2, sub = c & 3;
      const unsigned short* g = Bp + (size_t)row * H_ + k0 + sub * 8;
      unsigned short* l = Ws + (size_t)(r * 256 + w * 64) * 8;
      __builtin_amdgcn_global_load_lds(
          (const __attribute__((address_space(1))) void*)g,
          (__attribute__((address_space(3))) void*)l, 16, 0, 0);
    }
    __syncthreads();
    bf16x8 af[2], wf[4];
#pragma unroll
    for (int i = 0; i < 2; ++i)
      af[i] = *(const bf16x8*)(As + (wrA + i * 16 + fr) * 32 + fq * 8);
#pragma unroll
    for (int j = 0; j < 4; ++j)
      wf[j] = *(const bf16x8*)(Ws + (wcB + j * 16 + fr) * 32 + fq * 8);
#pragma unroll
    for (int i = 0; i < 2; ++i)
#pragma unroll
      for (int j = 0; j < 4; ++j)
        acc[i][j] = __builtin_amdgcn_mfma_f32_16x16x32_bf16(af[i], wf[j], acc[i][j], 0, 0, 0);
    __syncthreads();
  }

  float red[2][4];
#pragma unroll
  for (int i = 0; i < 2; ++i)
#pragma unroll
    for (int r = 0; r < 4; ++r) {
      float mx = acc[i][0][r];
#pragma unroll
      for (int j = 1; j < 4; ++j) mx = fmaxf(mx, acc[i][j][r]);
      mx = fmaxf(mx, __shfl_xor(mx, 1));
      mx = fmaxf(mx, __shfl_xor(mx, 2));
      mx = fmaxf(mx, __shfl_xor(mx, 4));
      mx = fmaxf(mx, __shfl_xor(mx, 8));
      if (fr == 0) pmS[w & 1][wrA + i * 16 + fq * 4 + r] = mx;
    }
  __syncthreads();
  float qm[4];
#pragma unroll
  for (int j = 0; j < 4; ++j) qm[j] = qmask[bb * Q_ + wcB + j * 16 + fr];
#pragma unroll
  for (int i = 0; i < 2; ++i)
#pragma unroll
    for (int r = 0; r < 4; ++r) {
      const int lr = wrA + i * 16 + fq * 4 + r;
      const float M = fmaxf(pmS[0][lr], pmS[1][lr]);
      if ((w & 1) == 0 && fr == 0) q2c[gm + lr] = M;  // b_att cancels in both softmaxes
      float s = 0.f;
#pragma unroll
      for (int j = 0; j < 4; ++j) {
        acc[i][j][r] = __expf(acc[i][j][r] - M);
        s += acc[i][j][r];
      }
      s += __shfl_xor(s, 1); s += __shfl_xor(s, 2);
      s += __shfl_xor(s, 4); s += __shfl_xor(s, 8);
      if (fr == 0) psS[w & 1][lr] = s;
    }
  __syncthreads();
#pragma unroll
  for (int i = 0; i < 2; ++i)
#pragma unroll
    for (int r = 0; r < 4; ++r) {
      const int lr = wrA + i * 16 + fq * 4 + r;
      const float S = psS[0][lr] + psS[1][lr];
      const float inv = cmask[gm + lr] / S;
#pragma unroll
      for (int j = 0; j < 4; ++j) {
        const int lc = wcB + j * 16 + fr;
        alpha[(size_t)(gm + lr) * Q_ + lc] = f2bf(acc[i][j][r] * inv * qm[j]);
      }
    }
}

// PV: 32x128 tile (grid 3072), K=128, NO LDS staging — B fragments read direct
// from global (qryT panels are L2-hot, 32 blocks reuse each). One barrier total.
// LDS only holds the 32x132 fp32 transpose buffer (16.9 KB).
// Epilogue writes all 4 output sections via NT float4 stores.
__global__ __launch_bounds__(256) void pv_kernel(
    const unsigned short* __restrict__ alpha, const unsigned short* __restrict__ qryT,
    const unsigned short* __restrict__ ctxp, const float* __restrict__ bvec,
    float* __restrict__ out32) {
  __shared__ __align__(16) float tr[32 * 132];
  const int tid = threadIdx.x;
  const int lane = tid & 63;
  const int w = tid >> 6;
  const int fr = lane & 15;
  const int fq = lane >> 4;
  const int orig = ((int)blockIdx.x & 7) * 384 + ((int)blockIdx.x >> 3);
  const int bb = orig / 192;
  const int rem = orig % 192;
  const int gm = bb * C_ + (rem / 6) * 32;
  const int gn = (rem % 6) * 128;
  const unsigned short* Ap = alpha + (size_t)gm * Q_;
  const unsigned short* Bp = qryT + ((size_t)bb * H_ + gn) * Q_;
  const int wrA = (w >> 1) * 16;
  const int wcB = (w & 1) * 64;

  // ctxp / bvec tile prefetch in WRITE layout (latency hides under MFMA)
  ushort4 cxr[4];
  f32x4 bvr[4];
#pragma unroll
  for (int k = 0; k < 4; ++k) {
    const int f = k * 256 + tid;
    const int row = f >> 5, c4 = (f & 31) << 2;
    cxr[k] = *(const ushort4*)&ctxp[(size_t)(gm + row) * H_ + gn + c4];
    bvr[k] = *(const f32x4*)&bvec[bb * H_ + gn + c4];
  }
  // alpha A-fragments (L2-hot)
  bf16x8 af[4];
#pragma unroll
  for (int kk = 0; kk < 4; ++kk)
    af[kk] = *(const bf16x8*)(Ap + (size_t)(wrA + fr) * Q_ + kk * 32 + fq * 8);

  f32x4 acc[4];
#pragma unroll
  for (int j = 0; j < 4; ++j)
#pragma unroll
    for (int e = 0; e < 4; ++e) acc[j][e] = 0.f;

  // B fragments direct from global, interleaved with MFMA
#pragma unroll
  for (int kk = 0; kk < 4; ++kk) {
    bf16x8 wf[4];
#pragma unroll
    for (int j = 0; j < 4; ++j)
      wf[j] = *(const bf16x8*)(Bp + (size_t)(wcB + j * 16 + fr) * Q_ + kk * 32 + fq * 8);
#pragma unroll
    for (int j = 0; j < 4; ++j)
      acc[j] = __builtin_amdgcn_mfma_f32_16x16x32_bf16(af[kk], wf[j], acc[j], 0, 0, 0);
  }

  // fp32 transpose -> coalesced layout
#pragma unroll
  for (int j = 0; j < 4; ++j)
#pragma unroll
    for (int r = 0; r < 4; ++r)
      tr[(wrA + fq * 4 + r) * 132 + wcB + j * 16 + fr] = acc[j][r];
  __syncthreads();

  // NT writes: 32 rows x 128 cols x 4 sections
#pragma unroll
  for (int k = 0; k < 4; ++k) {
    const int f = k * 256 + tid;
    const int row = f >> 5, c4 = (f & 31) << 2;
    f32x4 av = *(const f32x4*)&tr[row * 132 + c4];
    const ushort4 cu = cxr[k];
    const f32x4 bv = bvr[k];
    const float cx0 = bf2f(cu.x), cx1 = bf2f(cu.y), cx2 = bf2f(cu.z), cx3 = bf2f(cu.w);
    float* rowp = out32 + (size_t)(gm + row) * OSTR + gn + c4;
    f32x4 cxv; cxv[0] = cx0; cxv[1] = cx1; cxv[2] = cx2; cxv[3] = cx3;
    __builtin_nontemporal_store(cxv, (f32x4*)&rowp[0]);
    __builtin_nontemporal_store(av, (f32x4*)&rowp[H_]);
    f32x4 cc;
    cc[0] = cx0 * av[0]; cc[1] = cx1 * av[1]; cc[2] = cx2 * av[2]; cc[3] = cx3 * av[3];
    __builtin_nontemporal_store(cc, (f32x4*)&rowp[2 * H_]);
    f32x4 dd;
    dd[0] = cx0 * bv[0]; dd[1] = cx1 * bv[1]; dd[2] = cx2 * bv[2]; dd[3] = cx3 * bv[3];
    __builtin_nontemporal_store(dd, (f32x4*)&rowp[3 * H_]);
  }
}

// beta softmax over c (per batch) + bvec[b,p] = sum_c beta[c]*ctx_bf16[b,c,p]
__global__ __launch_bounds__(256) void beta_bvec_kernel(
    const unsigned short* __restrict__ ctxp, const float* __restrict__ q2c,
    const float* __restrict__ cmask, float* __restrict__ bvec) {
  __shared__ float sh[C_];
  __shared__ float red[256];
  const int tid = threadIdx.x;
  const int b = blockIdx.x / 12;
  const int p0 = (blockIdx.x % 12) * 64;
  float v[4];
  float lm = -1e30f;
#pragma unroll
  for (int i = 0; i < 4; ++i) {
    v[i] = q2c[b * C_ + i * 256 + tid];
    lm = fmaxf(lm, v[i]);
  }
  red[tid] = lm;
  __syncthreads();
  for (int off = 128; off > 0; off >>= 1) {
    if (tid < off) red[tid] = fmaxf(red[tid], red[tid + off]);
    __syncthreads();
  }
  const float m = red[0];
  __syncthreads();
  float ls = 0.f;
#pragma unroll
  for (int i = 0; i < 4; ++i) {
    float e = __expf(v[i] - m);
    sh[i * 256 + tid] = e * cmask[b * C_ + i * 256 + tid];
    ls += e;
  }
  red[tid] = ls;
  __syncthreads();
  for (int off = 128; off > 0; off >>= 1) {
    if (tid < off) red[tid] += red[tid + off];
    __syncthreads();
  }
  const float denom = red[0];
  const int pp = tid & 63;
  const int cg = tid >> 6;
  const unsigned short* base = ctxp + ((size_t)(b * C_ + cg)) * H_ + p0 + pp;
  float acc = 0.f;
#pragma unroll 4
  for (int c = cg; c < C_; c += 4) {
    acc += sh[c] * bf2f(*base);
    base += (size_t)4 * H_;
  }
  __syncthreads();
  red[tid] = acc;
  __syncthreads();
  if (tid < 64)
    bvec[b * H_ + p0 + tid] =
        (red[tid] + red[tid + 64] + red[tid + 128] + red[tid + 192]) / denom;
}

extern "C" void kernel_launch(void* const* d_in, const int* in_sizes, int n_in,
                              void* d_out, int out_size, void* d_ws, size_t ws_size,
                              hipStream_t stream) {
  const float* context = (const float*)d_in[0];
  const float* cmask   = (const float*)d_in[1];
  const float* query   = (const float*)d_in[2];
  const float* qmask   = (const float*)d_in[3];
  const float* Wc      = (const float*)d_in[4];
  const float* bc      = (const float*)d_in[5];
  const float* Wq      = (const float*)d_in[6];
  const float* bq      = (const float*)d_in[7];
  const float* w_att   = (const float*)d_in[8];
  float* out = (float*)d_out;

  unsigned short* ws_ctxb = (unsigned short*)d_ws;
  unsigned short* ws_qinb = ws_ctxb + (size_t)B_ * C_ * H_;
  unsigned short* ws_Wcb  = ws_qinb + (size_t)B_ * Q_ * H_;
  unsigned short* ws_Wqb  = ws_Wcb + (size_t)H_ * H_;
  unsigned short* ws_qryW = ws_Wqb + (size_t)H_ * H_;
  unsigned short* ws_qryT = ws_qryW + (size_t)B_ * Q_ * H_;
  unsigned short* ws_ctxp = ws_qryT + (size_t)B_ * H_ * Q_;
  float* ws_q2c  = (float*)(ws_ctxp + (size_t)B_ * C_ * H_);
  float* ws_bvec = ws_q2c + (size_t)B_ * C_;
  unsigned short* ws_alpha = ws_qinb;  // overlays dead qinb+Wcb

  {
    const int n0 = B_ * C_ * H_ / 8;
    const int n1 = B_ * Q_ * H_ / 8;
    const int n2 = H_ * H_ / 8;
    const int n3 = n2;
    const int tot = n0 + n1 + n2 + n3;
    f2bf4_kernel<<<(tot + 255) / 256, 256, 0, stream>>>(
        context, ws_ctxb, n0, query, ws_qinb, n1, Wc, ws_Wcb, n2, Wq, ws_Wqb, n3);
  }
  // combined projections: ctx (768 blocks) + qry (96 blocks), one launch.
  proj_kernel<<<864, 256, 0, stream>>>(
      ws_ctxb, ws_Wcb, bc, ws_ctxp, ws_qinb, ws_Wqb, bq, ws_qryW, ws_qryT, w_att);
  // sim GEMM + fused softmax: alpha bf16 + q2c. 256 blocks (64-row).
  sim_kernel<<<256, 256, 0, stream>>>(
      ws_ctxp, ws_qryW, ws_alpha, cmask, qmask, ws_q2c);
  // beta softmax + bvec (reads bf16 ctxp). 192 blocks.
  beta_bvec_kernel<<<B_ * 12, 256, 0, stream>>>(ws_ctxp, ws_q2c, cmask, ws_bvec);
  // PV: direct-global B, 1 barrier, NT writes of all 4 sections. 3072 blocks.
  pv_kernel<<<3072, 256, 0, stream>>>(ws_alpha, ws_qryT, ws_ctxp, ws_bvec, out);
}

// Round 18
// 140.958 us; speedup vs baseline: 1.0473x; 1.0473x over previous
//
#include <hip/hip_runtime.h>
#include <cstdint>

#define B_ 16
#define C_ 1024
#define Q_ 128
#define H_ 768
#define OSTR (4 * H_)  // 3072

typedef __attribute__((ext_vector_type(8))) short bf16x8;
typedef __attribute__((ext_vector_type(4))) float f32x4;
typedef __attribute__((ext_vector_type(4))) int int4v;

__device__ __forceinline__ unsigned short f2bf(float x) {
  union { float f; unsigned u; } v; v.f = x;
  unsigned r = v.u + 0x7FFFu + ((v.u >> 16) & 1u);
  return (unsigned short)(r >> 16);
}
__device__ __forceinline__ unsigned pk2(float a, float b) {
  return (unsigned)f2bf(a) | ((unsigned)f2bf(b) << 16);
}
__device__ __forceinline__ float bf2f(unsigned short u) {
  union { unsigned u; float f; } t; t.u = ((unsigned)u) << 16; return t.f;
}

// four-segment fp32 -> bf16 (context, query, Wc, Wq); NT loads.
__global__ __launch_bounds__(256) void f2bf4_kernel(
    const float* __restrict__ s0, unsigned short* __restrict__ d0, int n0,
    const float* __restrict__ s1, unsigned short* __restrict__ d1, int n1,
    const float* __restrict__ s2, unsigned short* __restrict__ d2, int n2,
    const float* __restrict__ s3, unsigned short* __restrict__ d3, int n3) {
  int i = blockIdx.x * 256 + threadIdx.x;
  const float* s;
  unsigned short* d;
  if (i < n0) { s = s0; d = d0; }
  else if ((i -= n0) < n1) { s = s1; d = d1; }
  else if ((i -= n1) < n2) { s = s2; d = d2; }
  else if ((i -= n2) < n3) { s = s3; d = d3; }
  else return;
  f32x4 a = __builtin_nontemporal_load((const f32x4*)s + 2 * i);
  f32x4 b = __builtin_nontemporal_load((const f32x4*)s + 2 * i + 1);
  int4v o;
  o[0] = (int)pk2(a[0], a[1]); o[1] = (int)pk2(a[2], a[3]);
  o[2] = (int)pk2(b[0], b[1]); o[3] = (int)pk2(b[2], b[3]);
  ((int4v*)d)[i] = o;
}

// Combined projection GEMM, one launch, 864 blocks:
//   blocks [0,768):  ctx proj -> bf16 ctxp (LDS bf16-transpose, int4v stores)
//   blocks [768,864): qry proj -> bf16 qryW=v*watt + bf16 qryT (transposed)
__global__ __launch_bounds__(256) void proj_kernel(
    const unsigned short* __restrict__ ctxb, const unsigned short* __restrict__ Wcb,
    const float* __restrict__ bc, unsigned short* __restrict__ ctxp,
    const unsigned short* __restrict__ qinb, const unsigned short* __restrict__ Wqb,
    const float* __restrict__ bq, unsigned short* __restrict__ qryW,
    unsigned short* __restrict__ qryT, const float* __restrict__ watt) {
  __shared__ __align__(16) unsigned char smem[33792];
  unsigned short* As = (unsigned short*)smem;
  unsigned short* Ws = (unsigned short*)(smem + 8192);
  const int tid = threadIdx.x;
  const int lane = tid & 63;
  const int w = tid >> 6;
  const int bid = (int)blockIdx.x;
  const bool isC = bid < 768;
  int orig, gm, gn;
  const unsigned short *Ap, *Bp;
  const float* bias;
  if (isC) {
    orig = (bid & 7) * 96 + (bid >> 3);
    gm = (orig / 6) * 128; gn = (orig % 6) * 128;
    Ap = ctxb + (size_t)gm * H_; Bp = Wcb + (size_t)gn * H_; bias = bc;
  } else {
    const int b2 = bid - 768;
    orig = (b2 & 7) * 12 + (b2 >> 3);
    gm = (orig / 6) * 128; gn = (orig % 6) * 128;
    Ap = qinb + (size_t)gm * H_; Bp = Wqb + (size_t)gn * H_; bias = bq;
  }
  const int wrA = (w >> 1) * 64;
  const int wcB = (w & 1) * 64;
  const int fr = lane & 15;
  const int fq = lane >> 4;

  auto stage128 = [&](const unsigned short* __restrict__ G, unsigned short* S, int k0) {
#pragma unroll
    for (int r = 0; r < 2; ++r) {
      const int c = r * 256 + tid;
      const int row = c >> 2, sub = c & 3;
      const unsigned short* g = G + (size_t)row * H_ + k0 + sub * 8;
      unsigned short* l = S + (size_t)(r * 256 + w * 64) * 8;  // wave-uniform base
      __builtin_amdgcn_global_load_lds(
          (const __attribute__((address_space(1))) void*)g,
          (__attribute__((address_space(3))) void*)l, 16, 0, 0);
    }
  };

  f32x4 acc[4][4];
#pragma unroll
  for (int i = 0; i < 4; ++i)
#pragma unroll
    for (int j = 0; j < 4; ++j)
#pragma unroll
      for (int e = 0; e < 4; ++e) acc[i][j][e] = 0.f;

  for (int k0 = 0; k0 < H_; k0 += 32) {
    stage128(Ap, As, k0);
    stage128(Bp, Ws, k0);
    __syncthreads();
    bf16x8 af[4], wf[4];
#pragma unroll
    for (int i = 0; i < 4; ++i)
      af[i] = *(const bf16x8*)(As + (wrA + i * 16 + fr) * 32 + fq * 8);
#pragma unroll
    for (int j = 0; j < 4; ++j)
      wf[j] = *(const bf16x8*)(Ws + (wcB + j * 16 + fr) * 32 + fq * 8);
#pragma unroll
    for (int i = 0; i < 4; ++i)
#pragma unroll
      for (int j = 0; j < 4; ++j)
        acc[i][j] = __builtin_amdgcn_mfma_f32_16x16x32_bf16(af[i], wf[j], acc[i][j], 0, 0, 0);
    __syncthreads();
  }

  if (isC) {
    unsigned short* tr16 = (unsigned short*)smem;
    float bj[4];
#pragma unroll
    for (int j = 0; j < 4; ++j) bj[j] = bias[gn + wcB + j * 16 + fr];
#pragma unroll
    for (int i = 0; i < 4; ++i)
#pragma unroll
      for (int j = 0; j < 4; ++j)
#pragma unroll
        for (int r = 0; r < 4; ++r)
          tr16[(wrA + i * 16 + fq * 4 + r) * 132 + wcB + j * 16 + fr] =
              f2bf(acc[i][j][r] + bj[j]);
    __syncthreads();
#pragma unroll
    for (int k = 0; k < 8; ++k) {
      const int f = k * 256 + tid;
      const int row = f >> 4, c8 = (f & 15) << 3;
      int4v v = *(const int4v*)&tr16[row * 132 + c8];
      *(int4v*)&ctxp[(size_t)(gm + row) * H_ + gn + c8] = v;
    }
  } else {
#pragma unroll
    for (int i = 0; i < 4; ++i) {
#pragma unroll
      for (int j = 0; j < 4; ++j) {
        const int n = gn + wcB + j * 16 + fr;
        const float bias_n = bias[n];
        const float wv = watt[n];
        ushort4 t4;
#pragma unroll
        for (int r = 0; r < 4; ++r) {
          const size_t m = (size_t)gm + wrA + i * 16 + fq * 4 + r;
          float v = acc[i][j][r] + bias_n;
          qryW[m * H_ + n] = f2bf(v * wv);
          (&t4.x)[r] = f2bf(v);
        }
        const int bidx = gm >> 7;
        const int q0 = wrA + i * 16 + fq * 4;
        *(ushort4*)(qryT + ((size_t)bidx * H_ + n) * Q_ + q0) = t4;
      }
    }
  }
}

// sim GEMM (64x128, full q) -> fused row-softmax -> bf16 alpha + q2c
__global__ __launch_bounds__(256) void sim_kernel(
    const unsigned short* __restrict__ A, const unsigned short* __restrict__ Bm,
    unsigned short* __restrict__ alpha, const float* __restrict__ cmask,
    const float* __restrict__ qmask, float* __restrict__ q2c) {
  __shared__ __align__(16) unsigned char smem[16384];
  __shared__ float pmS[2][64];
  __shared__ float psS[2][64];
  unsigned short* As = (unsigned short*)smem;
  unsigned short* Ws = (unsigned short*)(smem + 4096);
  const int tid = threadIdx.x;
  const int lane = tid & 63;
  const int w = tid >> 6;
  const int orig = ((int)blockIdx.x & 7) * 32 + ((int)blockIdx.x >> 3);
  const int bb = orig >> 4;
  const int gm = bb * C_ + (orig & 15) * 64;
  const int wrA = (w >> 1) * 32;
  const int wcB = (w & 1) * 64;
  const int fr = lane & 15;
  const int fq = lane >> 4;
  const unsigned short* Ap = A + (size_t)gm * H_;
  const unsigned short* Bp = Bm + (size_t)bb * Q_ * H_;

  f32x4 acc[2][4];
#pragma unroll
  for (int i = 0; i < 2; ++i)
#pragma unroll
    for (int j = 0; j < 4; ++j)
#pragma unroll
      for (int e = 0; e < 4; ++e) acc[i][j][e] = 0.f;

  for (int k0 = 0; k0 < H_; k0 += 32) {
    {
      const int row = tid >> 2, sub = tid & 3;
      const unsigned short* g = Ap + (size_t)row * H_ + k0 + sub * 8;
      unsigned short* l = As + (size_t)(w * 64) * 8;
      __builtin_amdgcn_global_load_lds(
          (const __attribute__((address_space(1))) void*)g,
          (__attribute__((address_space(3))) void*)l, 16, 0, 0);
    }
#pragma unroll
    for (int r = 0; r < 2; ++r) {
      const int c = r * 256 + tid;
      const int row = c >> 2, sub = c & 3;
      const unsigned short* g = Bp + (size_t)row * H_ + k0 + sub * 8;
      unsigned short* l = Ws + (size_t)(r * 256 + w * 64) * 8;
      __builtin_amdgcn_global_load_lds(
          (const __attribute__((address_space(1))) void*)g,
          (__attribute__((address_space(3))) void*)l, 16, 0, 0);
    }
    __syncthreads();
    bf16x8 af[2], wf[4];
#pragma unroll
    for (int i = 0; i < 2; ++i)
      af[i] = *(const bf16x8*)(As + (wrA + i * 16 + fr) * 32 + fq * 8);
#pragma unroll
    for (int j = 0; j < 4; ++j)
      wf[j] = *(const bf16x8*)(Ws + (wcB + j * 16 + fr) * 32 + fq * 8);
#pragma unroll
    for (int i = 0; i < 2; ++i)
#pragma unroll
      for (int j = 0; j < 4; ++j)
        acc[i][j] = __builtin_amdgcn_mfma_f32_16x16x32_bf16(af[i], wf[j], acc[i][j], 0, 0, 0);
    __syncthreads();
  }

  float red[2][4];
#pragma unroll
  for (int i = 0; i < 2; ++i)
#pragma unroll
    for (int r = 0; r < 4; ++r) {
      float mx = acc[i][0][r];
#pragma unroll
      for (int j = 1; j < 4; ++j) mx = fmaxf(mx, acc[i][j][r]);
      mx = fmaxf(mx, __shfl_xor(mx, 1));
      mx = fmaxf(mx, __shfl_xor(mx, 2));
      mx = fmaxf(mx, __shfl_xor(mx, 4));
      mx = fmaxf(mx, __shfl_xor(mx, 8));
      if (fr == 0) pmS[w & 1][wrA + i * 16 + fq * 4 + r] = mx;
    }
  __syncthreads();
  float qm[4];
#pragma unroll
  for (int j = 0; j < 4; ++j) qm[j] = qmask[bb * Q_ + wcB + j * 16 + fr];
#pragma unroll
  for (int i = 0; i < 2; ++i)
#pragma unroll
    for (int r = 0; r < 4; ++r) {
      const int lr = wrA + i * 16 + fq * 4 + r;
      const float M = fmaxf(pmS[0][lr], pmS[1][lr]);
      if ((w & 1) == 0 && fr == 0) q2c[gm + lr] = M;  // b_att cancels in both softmaxes
      float s = 0.f;
#pragma unroll
      for (int j = 0; j < 4; ++j) {
        acc[i][j][r] = __expf(acc[i][j][r] - M);
        s += acc[i][j][r];
      }
      s += __shfl_xor(s, 1); s += __shfl_xor(s, 2);
      s += __shfl_xor(s, 4); s += __shfl_xor(s, 8);
      if (fr == 0) psS[w & 1][lr] = s;
    }
  __syncthreads();
#pragma unroll
  for (int i = 0; i < 2; ++i)
#pragma unroll
    for (int r = 0; r < 4; ++r) {
      const int lr = wrA + i * 16 + fq * 4 + r;
      const float S = psS[0][lr] + psS[1][lr];
      const float inv = cmask[gm + lr] / S;
#pragma unroll
      for (int j = 0; j < 4; ++j) {
        const int lc = wcB + j * 16 + fr;
        alpha[(size_t)(gm + lr) * Q_ + lc] = f2bf(acc[i][j][r] * inv * qm[j]);
      }
    }
}

// PV: a = alpha @ qryT^T, 32x128 tile (grid 3072), K=128, no staged K-loop.
// B panel (32KB) staged once; alpha frags direct from global (L2-hot);
// all 4 output sections written via NT float4 stores.
__global__ __launch_bounds__(256) void pv_kernel(
    const unsigned short* __restrict__ alpha, const unsigned short* __restrict__ qryT,
    const unsigned short* __restrict__ ctxp, const float* __restrict__ bvec,
    float* __restrict__ out32) {
  __shared__ __align__(16) unsigned char smem[33792];
  const int tid = threadIdx.x;
  const int lane = tid & 63;
  const int w = tid >> 6;
  const int fr = lane & 15;
  const int fq = lane >> 4;
  const int orig = ((int)blockIdx.x & 7) * 384 + ((int)blockIdx.x >> 3);
  const int bb = orig / 192;
  const int rem = orig % 192;
  const int gm = bb * C_ + (rem / 6) * 32;
  const int gn = (rem % 6) * 128;
  const unsigned short* Ap = alpha + (size_t)gm * Q_;
  const unsigned short* Bp = qryT + ((size_t)bb * H_ + gn) * Q_;
  const int wrA = (w >> 1) * 16;
  const int wcB = (w & 1) * 64;
  unsigned short* Ws = (unsigned short*)smem;

  // stage full B panel (128 x 128 bf16 = 32 KB) via async gload_lds, one drain
#pragma unroll
  for (int kk = 0; kk < 4; ++kk) {
#pragma unroll
    for (int r = 0; r < 2; ++r) {
      const int c = r * 256 + tid;
      const int row = c >> 2, sub = c & 3;
      const unsigned short* g = Bp + (size_t)row * Q_ + kk * 32 + sub * 8;
      unsigned short* l = Ws + kk * 4096 + (size_t)(r * 256 + w * 64) * 8;
      __builtin_amdgcn_global_load_lds(
          (const __attribute__((address_space(1))) void*)g,
          (__attribute__((address_space(3))) void*)l, 16, 0, 0);
    }
  }
  // ctxp tile prefetch in output layout (hides under MFMA phase)
  ushort4 cxr[4];
  f32x4 bvr[4];
#pragma unroll
  for (int k = 0; k < 4; ++k) {
    const int f = k * 256 + tid;
    const int row = f >> 5, c4 = (f & 31) << 2;
    cxr[k] = *(const ushort4*)&ctxp[(size_t)(gm + row) * H_ + gn + c4];
    bvr[k] = *(const f32x4*)&bvec[bb * H_ + gn + c4];
  }
  // alpha fragments direct from global
  bf16x8 af[4];
#pragma unroll
  for (int kk = 0; kk < 4; ++kk)
    af[kk] = *(const bf16x8*)(Ap + (size_t)(wrA + fr) * Q_ + kk * 32 + fq * 8);

  f32x4 acc[4];
#pragma unroll
  for (int j = 0; j < 4; ++j)
#pragma unroll
    for (int e = 0; e < 4; ++e) acc[j][e] = 0.f;

  __syncthreads();  // B panel resident
#pragma unroll
  for (int kk = 0; kk < 4; ++kk) {
    bf16x8 wf[4];
#pragma unroll
    for (int j = 0; j < 4; ++j)
      wf[j] = *(const bf16x8*)(Ws + kk * 4096 + (wcB + j * 16 + fr) * 32 + fq * 8);
#pragma unroll
    for (int j = 0; j < 4; ++j)
      acc[j] = __builtin_amdgcn_mfma_f32_16x16x32_bf16(af[kk], wf[j], acc[j], 0, 0, 0);
  }
  __syncthreads();  // done reading Ws; reuse as fp32 transpose buffer

  float* tr = (float*)smem;
#pragma unroll
  for (int j = 0; j < 4; ++j)
#pragma unroll
    for (int r = 0; r < 4; ++r)
      tr[(wrA + fq * 4 + r) * 132 + wcB + j * 16 + fr] = acc[j][r];
  __syncthreads();
#pragma unroll
  for (int k = 0; k < 4; ++k) {
    const int f = k * 256 + tid;
    const int row = f >> 5, c4 = (f & 31) << 2;
    f32x4 av = *(const f32x4*)&tr[row * 132 + c4];
    const ushort4 cu = cxr[k];
    const f32x4 bv = bvr[k];
    const float cx0 = bf2f(cu.x), cx1 = bf2f(cu.y), cx2 = bf2f(cu.z), cx3 = bf2f(cu.w);
    float* rowp = out32 + (size_t)(gm + row) * OSTR + gn + c4;
    f32x4 cxv; cxv[0] = cx0; cxv[1] = cx1; cxv[2] = cx2; cxv[3] = cx3;
    __builtin_nontemporal_store(cxv, (f32x4*)&rowp[0]);
    __builtin_nontemporal_store(av, (f32x4*)&rowp[H_]);
    f32x4 cc;
    cc[0] = cx0 * av[0]; cc[1] = cx1 * av[1]; cc[2] = cx2 * av[2]; cc[3] = cx3 * av[3];
    __builtin_nontemporal_store(cc, (f32x4*)&rowp[2 * H_]);
    f32x4 dd;
    dd[0] = cx0 * bv[0]; dd[1] = cx1 * bv[1]; dd[2] = cx2 * bv[2]; dd[3] = cx3 * bv[3];
    __builtin_nontemporal_store(dd, (f32x4*)&rowp[3 * H_]);
  }
}

// beta softmax over c (per batch) + bvec[b,p] = sum_c beta[c]*ctx_bf16[b,c,p]
__global__ __launch_bounds__(256) void beta_bvec_kernel(
    const unsigned short* __restrict__ ctxp, const float* __restrict__ q2c,
    const float* __restrict__ cmask, float* __restrict__ bvec) {
  __shared__ float sh[C_];
  __shared__ float red[256];
  const int tid = threadIdx.x;
  const int b = blockIdx.x / 12;
  const int p0 = (blockIdx.x % 12) * 64;
  float v[4];
  float lm = -1e30f;
#pragma unroll
  for (int i = 0; i < 4; ++i) {
    v[i] = q2c[b * C_ + i * 256 + tid];
    lm = fmaxf(lm, v[i]);
  }
  red[tid] = lm;
  __syncthreads();
  for (int off = 128; off > 0; off >>= 1) {
    if (tid < off) red[tid] = fmaxf(red[tid], red[tid + off]);
    __syncthreads();
  }
  const float m = red[0];
  __syncthreads();
  float ls = 0.f;
#pragma unroll
  for (int i = 0; i < 4; ++i) {
    float e = __expf(v[i] - m);
    sh[i * 256 + tid] = e * cmask[b * C_ + i * 256 + tid];
    ls += e;
  }
  red[tid] = ls;
  __syncthreads();
  for (int off = 128; off > 0; off >>= 1) {
    if (tid < off) red[tid] += red[tid + off];
    __syncthreads();
  }
  const float denom = red[0];
  const int pp = tid & 63;
  const int cg = tid >> 6;
  const unsigned short* base = ctxp + ((size_t)(b * C_ + cg)) * H_ + p0 + pp;
  float acc = 0.f;
#pragma unroll 4
  for (int c = cg; c < C_; c += 4) {
    acc += sh[c] * bf2f(*base);
    base += (size_t)4 * H_;
  }
  __syncthreads();
  red[tid] = acc;
  __syncthreads();
  if (tid < 64)
    bvec[b * H_ + p0 + tid] =
        (red[tid] + red[tid + 64] + red[tid + 128] + red[tid + 192]) / denom;
}

extern "C" void kernel_launch(void* const* d_in, const int* in_sizes, int n_in,
                              void* d_out, int out_size, void* d_ws, size_t ws_size,
                              hipStream_t stream) {
  const float* context = (const float*)d_in[0];
  const float* cmask   = (const float*)d_in[1];
  const float* query   = (const float*)d_in[2];
  const float* qmask   = (const float*)d_in[3];
  const float* Wc      = (const float*)d_in[4];
  const float* bc      = (const float*)d_in[5];
  const float* Wq      = (const float*)d_in[6];
  const float* bq      = (const float*)d_in[7];
  const float* w_att   = (const float*)d_in[8];
  float* out = (float*)d_out;

  unsigned short* ws_ctxb = (unsigned short*)d_ws;
  unsigned short* ws_qinb = ws_ctxb + (size_t)B_ * C_ * H_;
  unsigned short* ws_Wcb  = ws_qinb + (size_t)B_ * Q_ * H_;
  unsigned short* ws_Wqb  = ws_Wcb + (size_t)H_ * H_;
  unsigned short* ws_qryW = ws_Wqb + (size_t)H_ * H_;
  unsigned short* ws_qryT = ws_qryW + (size_t)B_ * Q_ * H_;
  unsigned short* ws_ctxp = ws_qryT + (size_t)B_ * H_ * Q_;
  float* ws_q2c  = (float*)(ws_ctxp + (size_t)B_ * C_ * H_);
  float* ws_bvec = ws_q2c + (size_t)B_ * C_;
  unsigned short* ws_alpha = ws_qinb;  // overlays dead qinb+Wcb

  {
    const int n0 = B_ * C_ * H_ / 8;
    const int n1 = B_ * Q_ * H_ / 8;
    const int n2 = H_ * H_ / 8;
    const int n3 = n2;
    const int tot = n0 + n1 + n2 + n3;
    f2bf4_kernel<<<(tot + 255) / 256, 256, 0, stream>>>(
        context, ws_ctxb, n0, query, ws_qinb, n1, Wc, ws_Wcb, n2, Wq, ws_Wqb, n3);
  }
  // combined projections: ctx (768 blocks) + qry (96 blocks), one launch.
  proj_kernel<<<864, 256, 0, stream>>>(
      ws_ctxb, ws_Wcb, bc, ws_ctxp, ws_qinb, ws_Wqb, bq, ws_qryW, ws_qryT, w_att);
  // sim GEMM + fused softmax: alpha bf16 + q2c. 256 blocks (64-row).
  sim_kernel<<<256, 256, 0, stream>>>(
      ws_ctxp, ws_qryW, ws_alpha, cmask, qmask, ws_q2c);
  // beta softmax + bvec (reads bf16 ctxp). 192 blocks.
  beta_bvec_kernel<<<B_ * 12, 256, 0, stream>>>(ws_ctxp, ws_q2c, cmask, ws_bvec);
  // PV: 32x128 tiles, B staged once, NT writes of all 4 sections. 3072 blocks.
  pv_kernel<<<3072, 256, 0, stream>>>(ws_alpha, ws_qryT, ws_ctxp, ws_bvec, out);
}